// Round 10
// baseline (425.644 us; speedup 1.0000x reference)
//
#include <hip/hip_runtime.h>

#define DIM   2048
#define SLEN  2048
#define BATCH 2
#define NHEAD 16
#define HDIM  128
#define MROWS (BATCH*SLEN)   // 4096

typedef __attribute__((ext_vector_type(8))) __bf16 bf16x8;
typedef __attribute__((ext_vector_type(4))) float  f32x4;
typedef __attribute__((ext_vector_type(8))) unsigned short u16x8;
typedef __attribute__((ext_vector_type(4))) unsigned short u16x4;

__device__ __forceinline__ unsigned short f2bf(float f) {
  union { float f; unsigned u; } v; v.f = f;
  unsigned r = v.u + 0x7FFFu + ((v.u >> 16) & 1u);   // RTNE
  return (unsigned short)(r >> 16);
}
__device__ __forceinline__ float bf2f(unsigned short h) {
  union { unsigned u; float f; } v; v.u = ((unsigned)h) << 16;
  return v.f;
}
__device__ __forceinline__ void gload16(const void* g, void* l) {
  __builtin_amdgcn_global_load_lds(
      (const __attribute__((address_space(1))) void*)g,
      (__attribute__((address_space(3))) void*)l, 16, 0, 0);
}

// ---------------- fp32 -> bf16 convert (vectorized) ----------------
__global__ __launch_bounds__(256) void conv_f32_bf16(
    const float* __restrict__ in, unsigned short* __restrict__ out, int n4) {
  int t = blockIdx.x * 256 + threadIdx.x;
  if (t >= n4) return;
  f32x4 v = *(const f32x4*)(in + (size_t)t * 4);
  u16x4 o;
  o[0] = f2bf(v[0]); o[1] = f2bf(v[1]); o[2] = f2bf(v[2]); o[3] = f2bf(v[3]);
  *(u16x4*)(out + (size_t)t * 4) = o;
}

// ---------------- bf16 GEMM: C[M][N] = A[M][K] * Bw[N][K]^T + bias ----------------
// OUT_MODE: 0 = f32 row-major, 1 = bf16 row-major, 2 = bf16 transposed-per-batch
template<int OUT_MODE>
__global__ __launch_bounds__(256) void gemm_bt(
    const unsigned short* __restrict__ A,
    const unsigned short* __restrict__ Bw,
    const float* __restrict__ bias,
    void* __restrict__ Cout, int M, int N, int K)
{
  __shared__ __align__(16) unsigned short As[128][32];
  __shared__ __align__(16) unsigned short Bs[128][32];
  const int tid  = threadIdx.x;
  const int lane = tid & 63;
  const int wid  = tid >> 6;
  const int wr   = wid >> 1, wc = wid & 1;
  const int lrow = lane >> 4, lcol = lane & 15;

  const int gx = gridDim.x;
  int bid = blockIdx.y * gx + blockIdx.x;
  int nwg = gx * gridDim.y;
  int swz = (bid & 7) * (nwg >> 3) + (bid >> 3);     // T1 (nwg%8==0)
  const int row0 = (swz % gx) * 128, col0 = (swz / gx) * 128;

  f32x4 acc[4][4] = {};

  const unsigned short* Ablk = A  + (size_t)row0 * K;
  const unsigned short* Bblk = Bw + (size_t)col0 * K;
  char* AsB = (char*)&As[0][0];
  char* BsB = (char*)&Bs[0][0];

  for (int k0 = 0; k0 < K; k0 += 32) {
#pragma unroll
    for (int r = 0; r < 2; ++r) {
      int f = r * 256 + tid;
      gload16(Ablk + (size_t)(f >> 2) * K + k0 + (f & 3) * 8, AsB + (r * 256 + wid * 64) * 16);
      gload16(Bblk + (size_t)(f >> 2) * K + k0 + (f & 3) * 8, BsB + (r * 256 + wid * 64) * 16);
    }
    __syncthreads();
    bf16x8 af[4], bfv[4];
#pragma unroll
    for (int m = 0; m < 4; ++m)
      af[m] = *(const bf16x8*)&As[wr * 64 + m * 16 + lcol][lrow * 8];
#pragma unroll
    for (int n = 0; n < 4; ++n)
      bfv[n] = *(const bf16x8*)&Bs[wc * 64 + n * 16 + lcol][lrow * 8];
#pragma unroll
    for (int m = 0; m < 4; ++m)
#pragma unroll
      for (int n = 0; n < 4; ++n)
        acc[m][n] = __builtin_amdgcn_mfma_f32_16x16x32_bf16(af[m], bfv[n], acc[m][n], 0, 0, 0);
    __syncthreads();
  }

#pragma unroll
  for (int m = 0; m < 4; ++m) {
#pragma unroll
    for (int n = 0; n < 4; ++n) {
      int col = col0 + wc * 64 + n * 16 + lcol;
      float bv = bias[col];
      if (OUT_MODE == 2) {
        int row = row0 + wr * 64 + m * 16 + lrow * 4;
        u16x4 o;
#pragma unroll
        for (int j = 0; j < 4; ++j) o[j] = f2bf(acc[m][n][j] + bv);
        *(u16x4*)((unsigned short*)Cout +
                  ((size_t)((row >> 11) * DIM + col)) * SLEN + (row & (SLEN - 1))) = o;
      } else {
#pragma unroll
        for (int j = 0; j < 4; ++j) {
          int row = row0 + wr * 64 + m * 16 + lrow * 4 + j;
          float val = acc[m][n][j] + bv;
          if (OUT_MODE == 1) ((unsigned short*)Cout)[(size_t)row * N + col] = f2bf(val);
          else               ((float*)Cout)[(size_t)row * N + col] = val;
        }
      }
    }
  }
}

// ---------------- fused QKV GEMM + RoPE epilogue ----------------
__global__ __launch_bounds__(256) void gemm_qkv(
    const unsigned short* __restrict__ A,
    const unsigned short* __restrict__ Bw3,   // [3*DIM][DIM] bf16
    const float* __restrict__ bq, const float* __restrict__ bk, const float* __restrict__ bv,
    const float* __restrict__ cosT, const float* __restrict__ sinT, float qscale,
    unsigned short* __restrict__ qout,
    unsigned short* __restrict__ kout,
    unsigned short* __restrict__ vtout)
{
  __shared__ __align__(16) unsigned short As[128][32];
  __shared__ __align__(16) unsigned short Bs[128][32];
  const int tid  = threadIdx.x;
  const int lane = tid & 63;
  const int wid  = tid >> 6;
  const int wr   = wid >> 1, wc = wid & 1;
  const int lrow = lane >> 4, lcol = lane & 15;

  int bid = blockIdx.y * 32 + blockIdx.x;            // grid (32,48), nwg=1536
  int swz = (bid & 7) * 192 + (bid >> 3);            // T1 bijective
  const int row0 = (swz & 31) * 128;
  const int by   = swz >> 5;
  const int seg  = by >> 4;             // 0=q, 1=k, 2=v
  const int col0 = (by & 15) * 128;     // column within segment

  f32x4 acc[4][4] = {};

  const unsigned short* Ablk = A   + (size_t)row0 * DIM;
  const unsigned short* Bblk = Bw3 + (size_t)by * 128 * DIM;
  char* AsB = (char*)&As[0][0];
  char* BsB = (char*)&Bs[0][0];

  for (int k0 = 0; k0 < DIM; k0 += 32) {
#pragma unroll
    for (int r = 0; r < 2; ++r) {
      int f = r * 256 + tid;
      gload16(Ablk + (size_t)(f >> 2) * DIM + k0 + (f & 3) * 8, AsB + (r * 256 + wid * 64) * 16);
      gload16(Bblk + (size_t)(f >> 2) * DIM + k0 + (f & 3) * 8, BsB + (r * 256 + wid * 64) * 16);
    }
    __syncthreads();
    bf16x8 af[4], bfv[4];
#pragma unroll
    for (int m = 0; m < 4; ++m)
      af[m] = *(const bf16x8*)&As[wr * 64 + m * 16 + lcol][lrow * 8];
#pragma unroll
    for (int n = 0; n < 4; ++n)
      bfv[n] = *(const bf16x8*)&Bs[wc * 64 + n * 16 + lcol][lrow * 8];
#pragma unroll
    for (int m = 0; m < 4; ++m)
#pragma unroll
      for (int n = 0; n < 4; ++n)
        acc[m][n] = __builtin_amdgcn_mfma_f32_16x16x32_bf16(af[m], bfv[n], acc[m][n], 0, 0, 0);
    __syncthreads();
  }

  if (seg == 2) {
#pragma unroll
    for (int m = 0; m < 4; ++m) {
#pragma unroll
      for (int n = 0; n < 4; ++n) {
        int col = col0 + wc * 64 + n * 16 + lcol;
        float bvv = bv[col];
        int row = row0 + wr * 64 + m * 16 + lrow * 4;
        u16x4 o;
#pragma unroll
        for (int j = 0; j < 4; ++j) o[j] = f2bf(acc[m][n][j] + bvv);
        *(u16x4*)(vtout + ((size_t)((row >> 11) * DIM + col)) * SLEN + (row & (SLEN - 1))) = o;
      }
    }
  } else {
    unsigned short* out = (seg == 0) ? qout : kout;
    const float* bias   = (seg == 0) ? bq : bk;
    const float  osc    = (seg == 0) ? qscale : 1.0f;
#pragma unroll
    for (int m = 0; m < 4; ++m) {
#pragma unroll
      for (int n = 0; n < 4; ++n) {
        int col = col0 + wc * 64 + n * 16 + lcol;
        float bvv = bias[col];
        int ip  = col >> 1;               // rotary pair index
        int odd = col & 1;
#pragma unroll
        for (int j = 0; j < 4; ++j) {
          int row = row0 + wr * 64 + m * 16 + lrow * 4 + j;
          int s   = row & (SLEN - 1);
          float v = acc[m][n][j] + bvv;
          float p = __shfl_xor(v, 1, 64);            // partner col (bias included)
          float c  = cosT[(size_t)s * (DIM / 2) + ip];
          float sn = sinT[(size_t)s * (DIM / 2) + ip];
          float o  = odd ? (v * c + p * sn) : (v * c - p * sn);
          out[(size_t)row * DIM + col] = f2bf(o * osc);
        }
      }
    }
  }
}

// ---------------- RoPE in-place (fallback path only) ----------------
__global__ __launch_bounds__(256) void rope_inplace(
    unsigned short* __restrict__ q,
    const float* __restrict__ cosT, const float* __restrict__ sinT, float scale) {
  int t   = blockIdx.x * 256 + threadIdx.x;
  int row = t >> 8;
  int e0  = (t & 255) * 8;
  int s   = row & (SLEN - 1);
  unsigned short* p = q + (size_t)row * DIM + e0;
  u16x8 v = *(u16x8*)p;
  f32x4 c  = *(const f32x4*)(cosT + (size_t)s * (DIM / 2) + (e0 >> 1));
  f32x4 sn = *(const f32x4*)(sinT + (size_t)s * (DIM / 2) + (e0 >> 1));
#pragma unroll
  for (int i = 0; i < 4; ++i) {
    float xe = bf2f(v[2 * i]), xo = bf2f(v[2 * i + 1]);
    float oe = (xe * c[i] - xo * sn[i]) * scale;
    float oo = (xo * c[i] + xe * sn[i]) * scale;
    v[2 * i] = f2bf(oe); v[2 * i + 1] = f2bf(oo);
  }
  *(u16x8*)p = v;
}

// ---------------- flash attention fwd ----------------
// grid (S/64, H, B), 128 thr (2 waves). Wave w owns 32 q-rows (2 sub-tiles of 16).
// Same qblock=64 / grid=1024 as the 192us baseline, but kf/vf fragments are
// shared across 2 q-sub-tiles -> per-CU LDS read traffic halves. LDS 40KB ->
// 4 blocks/CU = 8 waves/CU (same occupancy as baseline). Pane-group T1 remap.
__global__ __launch_bounds__(128) void attn_fwd(
    const unsigned short* __restrict__ Q,
    const unsigned short* __restrict__ Kg,
    const unsigned short* __restrict__ VtG,   // [(b*DIM + e)][SLEN]
    const float* __restrict__ mask,
    unsigned short* __restrict__ O)
{
  __shared__ __align__(16) unsigned short Ks[64][128];    // 16 KB
  __shared__ __align__(16) unsigned short Vts[128][64];   // 16 KB
  __shared__ __align__(16) unsigned short Ps[2][32][64];  // 8 KB per-wave P (32 q-rows)

  // T1 pane-grouping remap (bijective on 1024 = 8 XCDs x 128)
  int s0 = blockIdx.x + 32 * (blockIdx.y + 16 * blockIdx.z);
  int xc = s0 & 7, jj = s0 >> 3;
  int pane = xc * 4 + (jj >> 5);
  const int qt = jj & 31;
  const int h  = pane & 15, b = pane >> 4;

  const int tid = threadIdx.x, lane = tid & 63, wid = tid >> 6;  // wid in {0,1}
  const int lrow = lane >> 4, lcol = lane & 15;
  const int sx = (lcol & 7) << 4;            // read/store XOR (row = lcol everywhere)

  const unsigned short* Qb  = Q  + ((size_t)(b * SLEN + qt * 64 + wid * 32)) * DIM + h * HDIM;
  const unsigned short* Kb  = Kg + (size_t)(b * SLEN) * DIM + h * HDIM;
  const unsigned short* Vtb = VtG + ((size_t)(b * DIM + h * HDIM)) * SLEN;
  const float* mrow0 = mask + (size_t)(qt * 64 + wid * 32 + lcol) * SLEN;

  bf16x8 qf[2][4];
#pragma unroll
  for (int qs = 0; qs < 2; ++qs)
#pragma unroll
    for (int kk = 0; kk < 4; ++kk)
      qf[qs][kk] = *(const bf16x8*)(Qb + (size_t)(qs * 16 + lcol) * DIM + kk * 32 + lrow * 8);

  float m_run[2] = {-1e30f, -1e30f}, l_run[2] = {0.f, 0.f};
  f32x4 acc_o[2][8] = {};

  char* KsB  = (char*)&Ks[0][0];
  char* VtsB = (char*)&Vts[0][0];
  char* PsB  = (char*)&Ps[0][0][0];

  for (int kt = 0; kt < SLEN / 64; ++kt) {
    __syncthreads();  // prior iteration's LDS reads done before overwrite
    // stage K tile: 1024 chunks / 128 thr = 8 each; swizzled SOURCE, linear dest
#pragma unroll
    for (int r = 0; r < 8; ++r) {
      int L = r * 128 + tid;
      int krow = L >> 4, kc = (L & 15) ^ (krow & 7);
      gload16(Kb + (size_t)(kt * 64 + krow) * DIM + kc * 8,
              KsB + (size_t)(r * 128 + wid * 64) * 16);
    }
#pragma unroll
    for (int r = 0; r < 8; ++r) {
      int L = r * 128 + tid;
      int d = L >> 3, vc = (L & 7) ^ (d & 7);
      gload16(Vtb + (size_t)d * SLEN + kt * 64 + vc * 8,
              VtsB + (size_t)(r * 128 + wid * 64) * 16);
    }
    __syncthreads();

    // S^T = K·Q^T for both q-sub-tiles; one kf read feeds 2 MFMAs
    f32x4 sacc[2][4] = {};
#pragma unroll
    for (int kn = 0; kn < 4; ++kn)
#pragma unroll
      for (int kk = 0; kk < 4; ++kk) {
        bf16x8 kf = *(const bf16x8*)(KsB + (size_t)(kn * 16 + lcol) * 256
                                         + ((kk * 64 + lrow * 16) ^ sx));
        sacc[0][kn] = __builtin_amdgcn_mfma_f32_16x16x32_bf16(kf, qf[0][kk], sacc[0][kn], 0, 0, 0);
        sacc[1][kn] = __builtin_amdgcn_mfma_f32_16x16x32_bf16(kf, qf[1][kk], sacc[1][kn], 0, 0, 0);
      }

#pragma unroll
    for (int qs = 0; qs < 2; ++qs) {
      // mask add (vectorized f32x4 per kn)
      float sv[16];
#pragma unroll
      for (int kn = 0; kn < 4; ++kn) {
        f32x4 mv = *(const f32x4*)(mrow0 + (size_t)qs * 16 * SLEN + kt * 64 + kn * 16 + lrow * 4);
#pragma unroll
        for (int r = 0; r < 4; ++r) sv[kn * 4 + r] = sacc[qs][kn][r] + mv[r];
      }

      // in-lane row max + 2 shfl
      float pmax = sv[0];
#pragma unroll
      for (int i = 1; i < 16; ++i) pmax = fmaxf(pmax, sv[i]);
      pmax = fmaxf(pmax, __shfl_xor(pmax, 16, 64));
      pmax = fmaxf(pmax, __shfl_xor(pmax, 32, 64));

      // defer-max (T13)
      if (!__all(pmax - m_run[qs] <= 8.0f)) {
        float mnew = fmaxf(m_run[qs], pmax);
        float alpha = __expf(m_run[qs] - mnew);
        m_run[qs] = mnew;
        l_run[qs] *= alpha;
        float ar[4];
#pragma unroll
        for (int r = 0; r < 4; ++r) ar[r] = __shfl(alpha, lrow * 4 + r, 64);
#pragma unroll
        for (int d = 0; d < 8; ++d) {
          f32x4 t = acc_o[qs][d];
#pragma unroll
          for (int r = 0; r < 4; ++r) t[r] *= ar[r];
          acc_o[qs][d] = t;
        }
      }

      // exp in place + row sum
      float rsum = 0.f;
#pragma unroll
      for (int i = 0; i < 16; ++i) { sv[i] = __expf(sv[i] - m_run[qs]); rsum += sv[i]; }
      rsum += __shfl_xor(rsum, 16, 64);
      rsum += __shfl_xor(rsum, 32, 64);
      l_run[qs] += rsum;

      // P store: row = qs*16 + lcol, keys kn*16+lrow*4+r -> u16x4 (XOR keeps 8B-aligned)
#pragma unroll
      for (int kn = 0; kn < 4; ++kn) {
        u16x4 o;
#pragma unroll
        for (int r = 0; r < 4; ++r) o[r] = f2bf(sv[kn * 4 + r]);
        *(u16x4*)(PsB + wid * 4096 + (qs * 16 + lcol) * 128
                  + ((kn * 32 + lrow * 8) ^ sx)) = o;
      }
    }
    // no barrier: Ps[wid] written+read by the same wave

    // PV: one vf read feeds 2 MFMAs
    bf16x8 pf[2][2];
#pragma unroll
    for (int qs = 0; qs < 2; ++qs)
#pragma unroll
      for (int ks = 0; ks < 2; ++ks)
        pf[qs][ks] = *(const bf16x8*)(PsB + wid * 4096 + (qs * 16 + lcol) * 128
                                      + ((ks * 64 + lrow * 16) ^ sx));
#pragma unroll
    for (int d = 0; d < 8; ++d)
#pragma unroll
      for (int ks = 0; ks < 2; ++ks) {
        bf16x8 vf = *(const bf16x8*)(VtsB + (size_t)(d * 16 + lcol) * 128
                                          + ((ks * 64 + lrow * 16) ^ sx));
        acc_o[0][d] = __builtin_amdgcn_mfma_f32_16x16x32_bf16(pf[0][ks], vf, acc_o[0][d], 0, 0, 0);
        acc_o[1][d] = __builtin_amdgcn_mfma_f32_16x16x32_bf16(pf[1][ks], vf, acc_o[1][d], 0, 0, 0);
      }
  }

  // epilogue
#pragma unroll
  for (int qs = 0; qs < 2; ++qs) {
    float linv[4];
#pragma unroll
    for (int r = 0; r < 4; ++r) linv[r] = 1.0f / __shfl(l_run[qs], lrow * 4 + r, 64);
    int orow0 = b * SLEN + qt * 64 + wid * 32 + qs * 16 + lrow * 4;
#pragma unroll
    for (int d = 0; d < 8; ++d)
#pragma unroll
      for (int r = 0; r < 4; ++r) {
        float o = acc_o[qs][d][r] * linv[r];
        O[(size_t)(orow0 + r) * DIM + h * HDIM + d * 16 + lcol] = f2bf(o);
      }
  }
}

// ---------------- launch ----------------
extern "C" void kernel_launch(void* const* d_in, const int* in_sizes, int n_in,
                              void* d_out, int out_size, void* d_ws, size_t ws_size,
                              hipStream_t stream) {
  const float* x    = (const float*)d_in[0];
  const float* cosT = (const float*)d_in[1];
  const float* sinT = (const float*)d_in[2];
  const float* mask = (const float*)d_in[3];
  const float* Wq   = (const float*)d_in[4];
  const float* bq   = (const float*)d_in[5];
  const float* Wk   = (const float*)d_in[6];
  const float* bk   = (const float*)d_in[7];
  const float* Wv   = (const float*)d_in[8];
  const float* bv   = (const float*)d_in[9];
  const float* Wo   = (const float*)d_in[10];
  const float* bo   = (const float*)d_in[11];

  const size_t MB = 1u << 20;
  if (ws_size < 72 * MB) return;

  char* ws = (char*)d_ws;
  unsigned short* xb = (unsigned short*)(ws);            // 16 MB (reused as Ob after attn)
  unsigned short* qb = (unsigned short*)(ws + 16 * MB);  // 16 MB
  unsigned short* kb = (unsigned short*)(ws + 32 * MB);  // 16 MB
  unsigned short* Vt = (unsigned short*)(ws + 48 * MB);  // 16 MB (V pre-transposed per head)
  unsigned short* Ob = xb;

  const float scale = 0.08838834764831845f;  // 1/sqrt(128)
  conv_f32_bf16<<<8192, 256, 0, stream>>>(x, xb, (MROWS * DIM) / 4);

  if (ws_size >= 88 * MB) {
    // fused QKV+RoPE path: Wb3 = [Wq;Wk;Wv] bf16 (24 MB)
    unsigned short* Wb3 = (unsigned short*)(ws + 64 * MB);
    conv_f32_bf16<<<4096, 256, 0, stream>>>(Wq, Wb3, (DIM * DIM) / 4);
    conv_f32_bf16<<<4096, 256, 0, stream>>>(Wk, Wb3 + (size_t)DIM * DIM, (DIM * DIM) / 4);
    conv_f32_bf16<<<4096, 256, 0, stream>>>(Wv, Wb3 + (size_t)2 * DIM * DIM, (DIM * DIM) / 4);
    gemm_qkv<<<dim3(MROWS / 128, 48), 256, 0, stream>>>(xb, Wb3, bq, bk, bv,
                                                        cosT, sinT, scale, qb, kb, Vt);
    attn_fwd<<<dim3(SLEN / 64, NHEAD, BATCH), 128, 0, stream>>>(qb, kb, Vt, mask, Ob);
    conv_f32_bf16<<<4096, 256, 0, stream>>>(Wo, Wb3, (DIM * DIM) / 4);
    gemm_bt<0><<<dim3(MROWS / 128, DIM / 128), 256, 0, stream>>>(Ob, Wb3, bo, d_out, MROWS, DIM, DIM);
  } else {
    // fallback (72 MB): unfused sequence
    unsigned short* Wb = (unsigned short*)(ws + 64 * MB);
    dim3 gGemm(MROWS / 128, DIM / 128);
    conv_f32_bf16<<<4096, 256, 0, stream>>>(Wq, Wb, (DIM * DIM) / 4);
    gemm_bt<1><<<gGemm, 256, 0, stream>>>(xb, Wb, bq, qb, MROWS, DIM, DIM);
    conv_f32_bf16<<<4096, 256, 0, stream>>>(Wk, Wb, (DIM * DIM) / 4);
    gemm_bt<1><<<gGemm, 256, 0, stream>>>(xb, Wb, bk, kb, MROWS, DIM, DIM);
    conv_f32_bf16<<<4096, 256, 0, stream>>>(Wv, Wb, (DIM * DIM) / 4);
    gemm_bt<2><<<gGemm, 256, 0, stream>>>(xb, Wb, bv, Vt, MROWS, DIM, DIM);
    rope_inplace<<<4096, 256, 0, stream>>>(qb, cosT, sinT, scale);
    rope_inplace<<<4096, 256, 0, stream>>>(kb, cosT, sinT, 1.0f);
    attn_fwd<<<dim3(SLEN / 64, NHEAD, BATCH), 128, 0, stream>>>(qb, kb, Vt, mask, Ob);
    conv_f32_bf16<<<4096, 256, 0, stream>>>(Wo, Wb, (DIM * DIM) / 4);
    gemm_bt<0><<<gGemm, 256, 0, stream>>>(Ob, Wb, bo, d_out, MROWS, DIM, DIM);
  }
}

// Round 11
// 398.640 us; speedup vs baseline: 1.0677x; 1.0677x over previous
//
#include <hip/hip_runtime.h>

#define DIM   2048
#define SLEN  2048
#define BATCH 2
#define NHEAD 16
#define HDIM  128
#define MROWS (BATCH*SLEN)   // 4096

typedef __attribute__((ext_vector_type(8))) __bf16 bf16x8;
typedef __attribute__((ext_vector_type(4))) float  f32x4;
typedef __attribute__((ext_vector_type(8))) unsigned short u16x8;
typedef __attribute__((ext_vector_type(4))) unsigned short u16x4;

__device__ __forceinline__ unsigned short f2bf(float f) {
  union { float f; unsigned u; } v; v.f = f;
  unsigned r = v.u + 0x7FFFu + ((v.u >> 16) & 1u);   // RTNE
  return (unsigned short)(r >> 16);
}
__device__ __forceinline__ float bf2f(unsigned short h) {
  union { unsigned u; float f; } v; v.u = ((unsigned)h) << 16;
  return v.f;
}
__device__ __forceinline__ void gload16(const void* g, void* l) {
  __builtin_amdgcn_global_load_lds(
      (const __attribute__((address_space(1))) void*)g,
      (__attribute__((address_space(3))) void*)l, 16, 0, 0);
}

// ---------------- fp32 -> bf16 convert (vectorized) ----------------
__global__ __launch_bounds__(256) void conv_f32_bf16(
    const float* __restrict__ in, unsigned short* __restrict__ out, int n4) {
  int t = blockIdx.x * 256 + threadIdx.x;
  if (t >= n4) return;
  f32x4 v = *(const f32x4*)(in + (size_t)t * 4);
  u16x4 o;
  o[0] = f2bf(v[0]); o[1] = f2bf(v[1]); o[2] = f2bf(v[2]); o[3] = f2bf(v[3]);
  *(u16x4*)(out + (size_t)t * 4) = o;
}

// ---------------- fused conversion: x + Wq + Wk + Wv in ONE dispatch ----------------
// grid = 8192 (x) + 3*4096 (weights) = 20480 blocks; branch is block-uniform.
__global__ __launch_bounds__(256) void conv4_f32_bf16(
    const float* __restrict__ x,
    const float* __restrict__ Wq, const float* __restrict__ Wk, const float* __restrict__ Wv,
    unsigned short* __restrict__ xb, unsigned short* __restrict__ Wb3) {
  int blk = blockIdx.x;
  const float* src; unsigned short* dst; int idx;
  if (blk < 8192)       { src = x;  dst = xb;                            idx = blk; }
  else if (blk < 12288) { src = Wq; dst = Wb3;                           idx = blk - 8192; }
  else if (blk < 16384) { src = Wk; dst = Wb3 + (size_t)DIM * DIM;       idx = blk - 12288; }
  else                  { src = Wv; dst = Wb3 + (size_t)2 * DIM * DIM;   idx = blk - 16384; }
  int t = idx * 256 + threadIdx.x;
  f32x4 v = *(const f32x4*)(src + (size_t)t * 4);
  u16x4 o;
  o[0] = f2bf(v[0]); o[1] = f2bf(v[1]); o[2] = f2bf(v[2]); o[3] = f2bf(v[3]);
  *(u16x4*)(dst + (size_t)t * 4) = o;
}

// ---------------- bf16 GEMM: C[M][N] = A[M][K] * Bw[N][K]^T + bias ----------------
// OUT_MODE: 0 = f32 row-major, 1 = bf16 row-major, 2 = bf16 transposed-per-batch
template<int OUT_MODE>
__global__ __launch_bounds__(256) void gemm_bt(
    const unsigned short* __restrict__ A,
    const unsigned short* __restrict__ Bw,
    const float* __restrict__ bias,
    void* __restrict__ Cout, int M, int N, int K)
{
  __shared__ __align__(16) unsigned short As[128][32];
  __shared__ __align__(16) unsigned short Bs[128][32];
  const int tid  = threadIdx.x;
  const int lane = tid & 63;
  const int wid  = tid >> 6;
  const int wr   = wid >> 1, wc = wid & 1;
  const int lrow = lane >> 4, lcol = lane & 15;

  const int gx = gridDim.x;
  int bid = blockIdx.y * gx + blockIdx.x;
  int nwg = gx * gridDim.y;
  int swz = (bid & 7) * (nwg >> 3) + (bid >> 3);     // T1 (nwg%8==0)
  const int row0 = (swz % gx) * 128, col0 = (swz / gx) * 128;

  f32x4 acc[4][4] = {};

  const unsigned short* Ablk = A  + (size_t)row0 * K;
  const unsigned short* Bblk = Bw + (size_t)col0 * K;
  char* AsB = (char*)&As[0][0];
  char* BsB = (char*)&Bs[0][0];

  for (int k0 = 0; k0 < K; k0 += 32) {
#pragma unroll
    for (int r = 0; r < 2; ++r) {
      int f = r * 256 + tid;
      gload16(Ablk + (size_t)(f >> 2) * K + k0 + (f & 3) * 8, AsB + (r * 256 + wid * 64) * 16);
      gload16(Bblk + (size_t)(f >> 2) * K + k0 + (f & 3) * 8, BsB + (r * 256 + wid * 64) * 16);
    }
    __syncthreads();
    bf16x8 af[4], bfv[4];
#pragma unroll
    for (int m = 0; m < 4; ++m)
      af[m] = *(const bf16x8*)&As[wr * 64 + m * 16 + lcol][lrow * 8];
#pragma unroll
    for (int n = 0; n < 4; ++n)
      bfv[n] = *(const bf16x8*)&Bs[wc * 64 + n * 16 + lcol][lrow * 8];
#pragma unroll
    for (int m = 0; m < 4; ++m)
#pragma unroll
      for (int n = 0; n < 4; ++n)
        acc[m][n] = __builtin_amdgcn_mfma_f32_16x16x32_bf16(af[m], bfv[n], acc[m][n], 0, 0, 0);
    __syncthreads();
  }

#pragma unroll
  for (int m = 0; m < 4; ++m) {
#pragma unroll
    for (int n = 0; n < 4; ++n) {
      int col = col0 + wc * 64 + n * 16 + lcol;
      float bv = bias[col];
      if (OUT_MODE == 2) {
        int row = row0 + wr * 64 + m * 16 + lrow * 4;
        u16x4 o;
#pragma unroll
        for (int j = 0; j < 4; ++j) o[j] = f2bf(acc[m][n][j] + bv);
        *(u16x4*)((unsigned short*)Cout +
                  ((size_t)((row >> 11) * DIM + col)) * SLEN + (row & (SLEN - 1))) = o;
      } else {
#pragma unroll
        for (int j = 0; j < 4; ++j) {
          int row = row0 + wr * 64 + m * 16 + lrow * 4 + j;
          float val = acc[m][n][j] + bv;
          if (OUT_MODE == 1) ((unsigned short*)Cout)[(size_t)row * N + col] = f2bf(val);
          else               ((float*)Cout)[(size_t)row * N + col] = val;
        }
      }
    }
  }
}

// ---------------- fused QKV GEMM + RoPE epilogue ----------------
__global__ __launch_bounds__(256) void gemm_qkv(
    const unsigned short* __restrict__ A,
    const unsigned short* __restrict__ Bw3,   // [3*DIM][DIM] bf16
    const float* __restrict__ bq, const float* __restrict__ bk, const float* __restrict__ bv,
    const float* __restrict__ cosT, const float* __restrict__ sinT, float qscale,
    unsigned short* __restrict__ qout,
    unsigned short* __restrict__ kout,
    unsigned short* __restrict__ vtout)
{
  __shared__ __align__(16) unsigned short As[128][32];
  __shared__ __align__(16) unsigned short Bs[128][32];
  const int tid  = threadIdx.x;
  const int lane = tid & 63;
  const int wid  = tid >> 6;
  const int wr   = wid >> 1, wc = wid & 1;
  const int lrow = lane >> 4, lcol = lane & 15;

  int bid = blockIdx.y * 32 + blockIdx.x;            // grid (32,48), nwg=1536
  int swz = (bid & 7) * 192 + (bid >> 3);            // T1 bijective
  const int row0 = (swz & 31) * 128;
  const int by   = swz >> 5;
  const int seg  = by >> 4;             // 0=q, 1=k, 2=v
  const int col0 = (by & 15) * 128;     // column within segment

  f32x4 acc[4][4] = {};

  const unsigned short* Ablk = A   + (size_t)row0 * DIM;
  const unsigned short* Bblk = Bw3 + (size_t)by * 128 * DIM;
  char* AsB = (char*)&As[0][0];
  char* BsB = (char*)&Bs[0][0];

  for (int k0 = 0; k0 < DIM; k0 += 32) {
#pragma unroll
    for (int r = 0; r < 2; ++r) {
      int f = r * 256 + tid;
      gload16(Ablk + (size_t)(f >> 2) * DIM + k0 + (f & 3) * 8, AsB + (r * 256 + wid * 64) * 16);
      gload16(Bblk + (size_t)(f >> 2) * DIM + k0 + (f & 3) * 8, BsB + (r * 256 + wid * 64) * 16);
    }
    __syncthreads();
    bf16x8 af[4], bfv[4];
#pragma unroll
    for (int m = 0; m < 4; ++m)
      af[m] = *(const bf16x8*)&As[wr * 64 + m * 16 + lcol][lrow * 8];
#pragma unroll
    for (int n = 0; n < 4; ++n)
      bfv[n] = *(const bf16x8*)&Bs[wc * 64 + n * 16 + lcol][lrow * 8];
#pragma unroll
    for (int m = 0; m < 4; ++m)
#pragma unroll
      for (int n = 0; n < 4; ++n)
        acc[m][n] = __builtin_amdgcn_mfma_f32_16x16x32_bf16(af[m], bfv[n], acc[m][n], 0, 0, 0);
    __syncthreads();
  }

  if (seg == 2) {
#pragma unroll
    for (int m = 0; m < 4; ++m) {
#pragma unroll
      for (int n = 0; n < 4; ++n) {
        int col = col0 + wc * 64 + n * 16 + lcol;
        float bvv = bv[col];
        int row = row0 + wr * 64 + m * 16 + lrow * 4;
        u16x4 o;
#pragma unroll
        for (int j = 0; j < 4; ++j) o[j] = f2bf(acc[m][n][j] + bvv);
        *(u16x4*)(vtout + ((size_t)((row >> 11) * DIM + col)) * SLEN + (row & (SLEN - 1))) = o;
      }
    }
  } else {
    unsigned short* out = (seg == 0) ? qout : kout;
    const float* bias   = (seg == 0) ? bq : bk;
    const float  osc    = (seg == 0) ? qscale : 1.0f;
#pragma unroll
    for (int m = 0; m < 4; ++m) {
#pragma unroll
      for (int n = 0; n < 4; ++n) {
        int col = col0 + wc * 64 + n * 16 + lcol;
        float bvv = bias[col];
        int ip  = col >> 1;               // rotary pair index
        int odd = col & 1;
#pragma unroll
        for (int j = 0; j < 4; ++j) {
          int row = row0 + wr * 64 + m * 16 + lrow * 4 + j;
          int s   = row & (SLEN - 1);
          float v = acc[m][n][j] + bvv;
          float p = __shfl_xor(v, 1, 64);            // partner col (bias included)
          float c  = cosT[(size_t)s * (DIM / 2) + ip];
          float sn = sinT[(size_t)s * (DIM / 2) + ip];
          float o  = odd ? (v * c + p * sn) : (v * c - p * sn);
          out[(size_t)row * DIM + col] = f2bf(o * osc);
        }
      }
    }
  }
}

// ---------------- RoPE in-place (fallback path only) ----------------
__global__ __launch_bounds__(256) void rope_inplace(
    unsigned short* __restrict__ q,
    const float* __restrict__ cosT, const float* __restrict__ sinT, float scale) {
  int t   = blockIdx.x * 256 + threadIdx.x;
  int row = t >> 8;
  int e0  = (t & 255) * 8;
  int s   = row & (SLEN - 1);
  unsigned short* p = q + (size_t)row * DIM + e0;
  u16x8 v = *(u16x8*)p;
  f32x4 c  = *(const f32x4*)(cosT + (size_t)s * (DIM / 2) + (e0 >> 1));
  f32x4 sn = *(const f32x4*)(sinT + (size_t)s * (DIM / 2) + (e0 >> 1));
#pragma unroll
  for (int i = 0; i < 4; ++i) {
    float xe = bf2f(v[2 * i]), xo = bf2f(v[2 * i + 1]);
    float oe = (xe * c[i] - xo * sn[i]) * scale;
    float oo = (xo * c[i] + xe * sn[i]) * scale;
    v[2 * i] = f2bf(oe); v[2 * i + 1] = f2bf(oo);
  }
  *(u16x8*)p = v;
}

// ---------------- flash attention fwd (round-9 verbatim: 189.6 us measured) ----
// grid (S/64, H, B) remapped so XCD c hosts (b,h)-panes 4c..4c+3.
__global__ __launch_bounds__(256) void attn_fwd(
    const unsigned short* __restrict__ Q,
    const unsigned short* __restrict__ Kg,
    const unsigned short* __restrict__ VtG,   // [(b*DIM + e)][SLEN]
    const float* __restrict__ mask,
    unsigned short* __restrict__ O)
{
  __shared__ __align__(16) unsigned short Ks[64][128];    // 16 KB
  __shared__ __align__(16) unsigned short Vts[128][64];   // 16 KB
  __shared__ __align__(16) unsigned short Ps[4][16][64];  // 8 KB per-wave P

  // T1 pane-grouping remap (bijective on 1024 = 8 XCDs x 128)
  int s0 = blockIdx.x + 32 * (blockIdx.y + 16 * blockIdx.z);
  int xc = s0 & 7, jj = s0 >> 3;
  int pane = xc * 4 + (jj >> 5);
  const int qt = jj & 31;
  const int h  = pane & 15, b = pane >> 4;

  const int tid = threadIdx.x, lane = tid & 63, wid = tid >> 6;
  const int lrow = lane >> 4, lcol = lane & 15;
  const int sx = (lcol & 7) << 4;            // read/store XOR (row = lcol everywhere)

  const unsigned short* Qb  = Q  + ((size_t)(b * SLEN + qt * 64)) * DIM + h * HDIM;
  const unsigned short* Kb  = Kg + (size_t)(b * SLEN) * DIM + h * HDIM;
  const unsigned short* Vtb = VtG + ((size_t)(b * DIM + h * HDIM)) * SLEN;
  const float* maskRow = mask + (size_t)(qt * 64 + wid * 16 + lcol) * SLEN;

  bf16x8 qf[4];
#pragma unroll
  for (int kk = 0; kk < 4; ++kk)
    qf[kk] = *(const bf16x8*)(Qb + (size_t)(wid * 16 + lcol) * DIM + kk * 32 + lrow * 8);

  float m_run = -1e30f, l_run = 0.f;   // per-lane, home q-row = lcol
  f32x4 acc_o[8] = {};

  char* KsB  = (char*)&Ks[0][0];
  char* VtsB = (char*)&Vts[0][0];
  char* PsB  = (char*)&Ps[0][0][0];

  for (int kt = 0; kt < SLEN / 64; ++kt) {
    __syncthreads();  // prior iteration's LDS reads done before overwrite
#pragma unroll
    for (int r = 0; r < 4; ++r) {
      int L = r * 256 + wid * 64 + lane;
      int krow = L >> 4, kc = (L & 15) ^ (krow & 7);
      gload16(Kb + (size_t)(kt * 64 + krow) * DIM + kc * 8,
              KsB + (size_t)(r * 256 + wid * 64) * 16);
    }
#pragma unroll
    for (int r = 0; r < 4; ++r) {
      int L = r * 256 + wid * 64 + lane;
      int d = L >> 3, vc = (L & 7) ^ (d & 7);
      gload16(Vtb + (size_t)d * SLEN + kt * 64 + vc * 8,
              VtsB + (size_t)(r * 256 + wid * 64) * 16);
    }
    __syncthreads();

    // S^T = K·Q^T: D[key][q], q = lcol, key = kn*16 + lrow*4 + r
    f32x4 sacc[4] = {};
#pragma unroll
    for (int kn = 0; kn < 4; ++kn)
#pragma unroll
      for (int kk = 0; kk < 4; ++kk) {
        bf16x8 kf = *(const bf16x8*)(KsB + (size_t)(kn * 16 + lcol) * 256
                                         + ((kk * 64 + lrow * 16) ^ sx));
        sacc[kn] = __builtin_amdgcn_mfma_f32_16x16x32_bf16(kf, qf[kk], sacc[kn], 0, 0, 0);
      }

    // mask add (vectorized f32x4 per kn)
    float sv[16];
#pragma unroll
    for (int kn = 0; kn < 4; ++kn) {
      f32x4 mv = *(const f32x4*)(maskRow + kt * 64 + kn * 16 + lrow * 4);
#pragma unroll
      for (int r = 0; r < 4; ++r) sv[kn * 4 + r] = sacc[kn][r] + mv[r];
    }

    // in-lane row max + 2 shfl (lanes lcol, lcol+16, lcol+32, lcol+48 share q-row)
    float pmax = sv[0];
#pragma unroll
    for (int i = 1; i < 16; ++i) pmax = fmaxf(pmax, sv[i]);
    pmax = fmaxf(pmax, __shfl_xor(pmax, 16, 64));
    pmax = fmaxf(pmax, __shfl_xor(pmax, 32, 64));

    // defer-max (T13): only rescale when some row's max grew past THR=8
    if (!__all(pmax - m_run <= 8.0f)) {
      float mnew = fmaxf(m_run, pmax);
      float alpha = __expf(m_run - mnew);
      m_run = mnew;
      l_run *= alpha;
      float ar[4];
#pragma unroll
      for (int r = 0; r < 4; ++r) ar[r] = __shfl(alpha, lrow * 4 + r, 64);
#pragma unroll
      for (int d = 0; d < 8; ++d) {
        f32x4 t = acc_o[d];
#pragma unroll
        for (int r = 0; r < 4; ++r) t[r] *= ar[r];
        acc_o[d] = t;
      }
    }

    // exp + row sum (in-lane + 2 shfl)
    float pv[16];
    float rsum = 0.f;
#pragma unroll
    for (int i = 0; i < 16; ++i) { float pe = __expf(sv[i] - m_run); pv[i] = pe; rsum += pe; }
    rsum += __shfl_xor(rsum, 16, 64);
    rsum += __shfl_xor(rsum, 32, 64);
    l_run += rsum;

    // P store: row = q = lcol, k = kn*16 + lrow*4 + r, swizzled by sx
#pragma unroll
    for (int kn = 0; kn < 4; ++kn)
#pragma unroll
      for (int r = 0; r < 4; ++r)
        *(unsigned short*)(PsB + wid * 2048 + lcol * 128
                           + ((kn * 32 + (lrow * 4 + r) * 2) ^ sx)) = f2bf(pv[kn * 4 + r]);
    // no barrier: Ps[wid] written+read by the same wave

    // PV: A = P (16x64), B = V^T rows (d)
    bf16x8 pf[2];
#pragma unroll
    for (int ks = 0; ks < 2; ++ks)
      pf[ks] = *(const bf16x8*)(PsB + wid * 2048 + lcol * 128
                                + ((ks * 64 + lrow * 16) ^ sx));
#pragma unroll
    for (int d = 0; d < 8; ++d)
#pragma unroll
      for (int ks = 0; ks < 2; ++ks) {
        bf16x8 vf = *(const bf16x8*)(VtsB + (size_t)(d * 16 + lcol) * 128
                                          + ((ks * 64 + lrow * 16) ^ sx));
        acc_o[d] = __builtin_amdgcn_mfma_f32_16x16x32_bf16(pf[ks], vf, acc_o[d], 0, 0, 0);
      }
  }

  // epilogue: O[q][d], q = wid*16 + lrow*4 + r, d = d*16 + lcol; l via shfl from home lanes
  float linv[4];
#pragma unroll
  for (int r = 0; r < 4; ++r) linv[r] = 1.0f / __shfl(l_run, lrow * 4 + r, 64);
  int orow0 = b * SLEN + qt * 64 + wid * 16 + lrow * 4;
#pragma unroll
  for (int d = 0; d < 8; ++d)
#pragma unroll
    for (int r = 0; r < 4; ++r) {
      float o = acc_o[d][r] * linv[r];
      O[(size_t)(orow0 + r) * DIM + h * HDIM + d * 16 + lcol] = f2bf(o);
    }
}

// ---------------- launch ----------------
extern "C" void kernel_launch(void* const* d_in, const int* in_sizes, int n_in,
                              void* d_out, int out_size, void* d_ws, size_t ws_size,
                              hipStream_t stream) {
  const float* x    = (const float*)d_in[0];
  const float* cosT = (const float*)d_in[1];
  const float* sinT = (const float*)d_in[2];
  const float* mask = (const float*)d_in[3];
  const float* Wq   = (const float*)d_in[4];
  const float* bq   = (const float*)d_in[5];
  const float* Wk   = (const float*)d_in[6];
  const float* bk   = (const float*)d_in[7];
  const float* Wv   = (const float*)d_in[8];
  const float* bv   = (const float*)d_in[9];
  const float* Wo   = (const float*)d_in[10];
  const float* bo   = (const float*)d_in[11];

  const size_t MB = 1u << 20;
  if (ws_size < 72 * MB) return;

  char* ws = (char*)d_ws;
  unsigned short* xb = (unsigned short*)(ws);            // 16 MB (reused as Ob after attn)
  unsigned short* qb = (unsigned short*)(ws + 16 * MB);  // 16 MB
  unsigned short* kb = (unsigned short*)(ws + 32 * MB);  // 16 MB
  unsigned short* Vt = (unsigned short*)(ws + 48 * MB);  // 16 MB (V pre-transposed per head)
  unsigned short* Ob = xb;

  const float scale = 0.08838834764831845f;  // 1/sqrt(128)

  if (ws_size >= 88 * MB) {
    // fused path: one conversion dispatch (x + Wq + Wk + Wv), fused QKV+RoPE GEMM
    unsigned short* Wb3 = (unsigned short*)(ws + 64 * MB);   // 24 MB
    conv4_f32_bf16<<<20480, 256, 0, stream>>>(x, Wq, Wk, Wv, xb, Wb3);
    gemm_qkv<<<dim3(MROWS / 128, 48), 256, 0, stream>>>(xb, Wb3, bq, bk, bv,
                                                        cosT, sinT, scale, qb, kb, Vt);
    attn_fwd<<<dim3(SLEN / 64, NHEAD, BATCH), 256, 0, stream>>>(qb, kb, Vt, mask, Ob);
    conv_f32_bf16<<<4096, 256, 0, stream>>>(Wo, Wb3, (DIM * DIM) / 4);
    gemm_bt<0><<<dim3(MROWS / 128, DIM / 128), 256, 0, stream>>>(Ob, Wb3, bo, d_out, MROWS, DIM, DIM);
  } else {
    // fallback (72 MB): unfused sequence
    unsigned short* Wb = (unsigned short*)(ws + 64 * MB);
    dim3 gGemm(MROWS / 128, DIM / 128);
    conv_f32_bf16<<<8192, 256, 0, stream>>>(x, xb, (MROWS * DIM) / 4);
    conv_f32_bf16<<<4096, 256, 0, stream>>>(Wq, Wb, (DIM * DIM) / 4);
    gemm_bt<1><<<gGemm, 256, 0, stream>>>(xb, Wb, bq, qb, MROWS, DIM, DIM);
    conv_f32_bf16<<<4096, 256, 0, stream>>>(Wk, Wb, (DIM * DIM) / 4);
    gemm_bt<1><<<gGemm, 256, 0, stream>>>(xb, Wb, bk, kb, MROWS, DIM, DIM);
    conv_f32_bf16<<<4096, 256, 0, stream>>>(Wv, Wb, (DIM * DIM) / 4);
    gemm_bt<2><<<gGemm, 256, 0, stream>>>(xb, Wb, bv, Vt, MROWS, DIM, DIM);
    rope_inplace<<<4096, 256, 0, stream>>>(qb, cosT, sinT, scale);
    rope_inplace<<<4096, 256, 0, stream>>>(kb, cosT, sinT, 1.0f);
    attn_fwd<<<dim3(SLEN / 64, NHEAD, BATCH), 256, 0, stream>>>(qb, kb, Vt, mask, Ob);
    conv_f32_bf16<<<4096, 256, 0, stream>>>(Wo, Wb, (DIM * DIM) / 4);
    gemm_bt<0><<<gGemm, 256, 0, stream>>>(Ob, Wb, bo, d_out, MROWS, DIM, DIM);
  }
}

// Round 12
// 381.423 us; speedup vs baseline: 1.1159x; 1.0451x over previous
//
#include <hip/hip_runtime.h>

#define DIM   2048
#define SLEN  2048
#define BATCH 2
#define NHEAD 16
#define HDIM  128
#define MROWS (BATCH*SLEN)   // 4096

typedef __attribute__((ext_vector_type(8))) __bf16 bf16x8;
typedef __attribute__((ext_vector_type(4))) float  f32x4;
typedef __attribute__((ext_vector_type(8))) unsigned short u16x8;
typedef __attribute__((ext_vector_type(4))) unsigned short u16x4;

__device__ __forceinline__ unsigned short f2bf(float f) {
  union { float f; unsigned u; } v; v.f = f;
  unsigned r = v.u + 0x7FFFu + ((v.u >> 16) & 1u);   // RTNE
  return (unsigned short)(r >> 16);
}
__device__ __forceinline__ float bf2f(unsigned short h) {
  union { unsigned u; float f; } v; v.u = ((unsigned)h) << 16;
  return v.f;
}
__device__ __forceinline__ void gload16(const void* g, void* l) {
  __builtin_amdgcn_global_load_lds(
      (const __attribute__((address_space(1))) void*)g,
      (__attribute__((address_space(3))) void*)l, 16, 0, 0);
}

// ---------------- fp32 -> bf16 convert (vectorized) ----------------
__global__ __launch_bounds__(256) void conv_f32_bf16(
    const float* __restrict__ in, unsigned short* __restrict__ out, int n4) {
  int t = blockIdx.x * 256 + threadIdx.x;
  if (t >= n4) return;
  f32x4 v = *(const f32x4*)(in + (size_t)t * 4);
  u16x4 o;
  o[0] = f2bf(v[0]); o[1] = f2bf(v[1]); o[2] = f2bf(v[2]); o[3] = f2bf(v[3]);
  *(u16x4*)(out + (size_t)t * 4) = o;
}

// ---------------- fused conversion: x + Wq + Wk + Wv in ONE dispatch ----------------
__global__ __launch_bounds__(256) void conv4_f32_bf16(
    const float* __restrict__ x,
    const float* __restrict__ Wq, const float* __restrict__ Wk, const float* __restrict__ Wv,
    unsigned short* __restrict__ xb, unsigned short* __restrict__ Wb3) {
  int blk = blockIdx.x;
  const float* src; unsigned short* dst; int idx;
  if (blk < 8192)       { src = x;  dst = xb;                            idx = blk; }
  else if (blk < 12288) { src = Wq; dst = Wb3;                           idx = blk - 8192; }
  else if (blk < 16384) { src = Wk; dst = Wb3 + (size_t)DIM * DIM;       idx = blk - 12288; }
  else                  { src = Wv; dst = Wb3 + (size_t)2 * DIM * DIM;   idx = blk - 16384; }
  int t = idx * 256 + threadIdx.x;
  f32x4 v = *(const f32x4*)(src + (size_t)t * 4);
  u16x4 o;
  o[0] = f2bf(v[0]); o[1] = f2bf(v[1]); o[2] = f2bf(v[2]); o[3] = f2bf(v[3]);
  *(u16x4*)(dst + (size_t)t * 4) = o;
}

// ---------------- bf16 GEMM (BK=64, swizzled staging): C = A * Bw^T + bias ----------------
// OUT_MODE: 0 = f32 row-major, 1 = bf16 row-major, 2 = bf16 transposed-per-batch
// 128-B LDS rows would be a 16-way conflict; source-swizzle c^=(row&7) (rule #21)
// + read XOR (lcol&7)<<4 makes it 2-way (free). BK=64 halves barrier drains.
template<int OUT_MODE>
__global__ __launch_bounds__(256) void gemm_bt(
    const unsigned short* __restrict__ A,
    const unsigned short* __restrict__ Bw,
    const float* __restrict__ bias,
    void* __restrict__ Cout, int M, int N, int K)
{
  __shared__ __align__(16) unsigned short As[128][64];   // 16 KB
  __shared__ __align__(16) unsigned short Bs[128][64];   // 16 KB
  const int tid  = threadIdx.x;
  const int lane = tid & 63;
  const int wid  = tid >> 6;
  const int wr   = wid >> 1, wc = wid & 1;
  const int lrow = lane >> 4, lcol = lane & 15;
  const int sx   = (lcol & 7) << 4;

  const int gx = gridDim.x;
  int bid = blockIdx.y * gx + blockIdx.x;
  int nwg = gx * gridDim.y;
  int swz = (bid & 7) * (nwg >> 3) + (bid >> 3);     // T1 (nwg%8==0)
  const int row0 = (swz % gx) * 128, col0 = (swz / gx) * 128;

  f32x4 acc[4][4] = {};

  const unsigned short* Ablk = A  + (size_t)row0 * K;
  const unsigned short* Bblk = Bw + (size_t)col0 * K;
  char* AsB = (char*)&As[0][0];
  char* BsB = (char*)&Bs[0][0];

  for (int k0 = 0; k0 < K; k0 += 64) {
#pragma unroll
    for (int r = 0; r < 4; ++r) {
      int L = r * 256 + wid * 64 + lane;               // chunk id; row=L>>3, c=L&7
      int row = L >> 3, cs = (L & 7) ^ (row & 7);
      gload16(Ablk + (size_t)row * K + k0 + cs * 8, AsB + (size_t)(r * 256 + wid * 64) * 16);
      gload16(Bblk + (size_t)row * K + k0 + cs * 8, BsB + (size_t)(r * 256 + wid * 64) * 16);
    }
    __syncthreads();
    bf16x8 af[4][2], bfv[4][2];
#pragma unroll
    for (int m = 0; m < 4; ++m)
#pragma unroll
      for (int kk = 0; kk < 2; ++kk)
        af[m][kk] = *(const bf16x8*)(AsB + (size_t)(wr * 64 + m * 16 + lcol) * 128
                                         + ((kk * 64 + lrow * 16) ^ sx));
#pragma unroll
    for (int n = 0; n < 4; ++n)
#pragma unroll
      for (int kk = 0; kk < 2; ++kk)
        bfv[n][kk] = *(const bf16x8*)(BsB + (size_t)(wc * 64 + n * 16 + lcol) * 128
                                          + ((kk * 64 + lrow * 16) ^ sx));
#pragma unroll
    for (int m = 0; m < 4; ++m)
#pragma unroll
      for (int n = 0; n < 4; ++n)
#pragma unroll
        for (int kk = 0; kk < 2; ++kk)
          acc[m][n] = __builtin_amdgcn_mfma_f32_16x16x32_bf16(af[m][kk], bfv[n][kk], acc[m][n], 0, 0, 0);
    __syncthreads();
  }

#pragma unroll
  for (int m = 0; m < 4; ++m) {
#pragma unroll
    for (int n = 0; n < 4; ++n) {
      int col = col0 + wc * 64 + n * 16 + lcol;
      float bv = bias[col];
      if (OUT_MODE == 2) {
        int row = row0 + wr * 64 + m * 16 + lrow * 4;
        u16x4 o;
#pragma unroll
        for (int j = 0; j < 4; ++j) o[j] = f2bf(acc[m][n][j] + bv);
        *(u16x4*)((unsigned short*)Cout +
                  ((size_t)((row >> 11) * DIM + col)) * SLEN + (row & (SLEN - 1))) = o;
      } else {
#pragma unroll
        for (int j = 0; j < 4; ++j) {
          int row = row0 + wr * 64 + m * 16 + lrow * 4 + j;
          float val = acc[m][n][j] + bv;
          if (OUT_MODE == 1) ((unsigned short*)Cout)[(size_t)row * N + col] = f2bf(val);
          else               ((float*)Cout)[(size_t)row * N + col] = val;
        }
      }
    }
  }
}

// ---------------- fused QKV GEMM + RoPE epilogue (BK=64, swizzled staging) ----------------
__global__ __launch_bounds__(256) void gemm_qkv(
    const unsigned short* __restrict__ A,
    const unsigned short* __restrict__ Bw3,   // [3*DIM][DIM] bf16
    const float* __restrict__ bq, const float* __restrict__ bk, const float* __restrict__ bv,
    const float* __restrict__ cosT, const float* __restrict__ sinT, float qscale,
    unsigned short* __restrict__ qout,
    unsigned short* __restrict__ kout,
    unsigned short* __restrict__ vtout)
{
  __shared__ __align__(16) unsigned short As[128][64];
  __shared__ __align__(16) unsigned short Bs[128][64];
  const int tid  = threadIdx.x;
  const int lane = tid & 63;
  const int wid  = tid >> 6;
  const int wr   = wid >> 1, wc = wid & 1;
  const int lrow = lane >> 4, lcol = lane & 15;
  const int sx   = (lcol & 7) << 4;

  int bid = blockIdx.y * 32 + blockIdx.x;            // grid (32,48), nwg=1536
  int swz = (bid & 7) * 192 + (bid >> 3);            // T1 bijective
  const int row0 = (swz & 31) * 128;
  const int by   = swz >> 5;
  const int seg  = by >> 4;             // 0=q, 1=k, 2=v
  const int col0 = (by & 15) * 128;     // column within segment

  f32x4 acc[4][4] = {};

  const unsigned short* Ablk = A   + (size_t)row0 * DIM;
  const unsigned short* Bblk = Bw3 + (size_t)by * 128 * DIM;
  char* AsB = (char*)&As[0][0];
  char* BsB = (char*)&Bs[0][0];

  for (int k0 = 0; k0 < DIM; k0 += 64) {
#pragma unroll
    for (int r = 0; r < 4; ++r) {
      int L = r * 256 + wid * 64 + lane;
      int row = L >> 3, cs = (L & 7) ^ (row & 7);
      gload16(Ablk + (size_t)row * DIM + k0 + cs * 8, AsB + (size_t)(r * 256 + wid * 64) * 16);
      gload16(Bblk + (size_t)row * DIM + k0 + cs * 8, BsB + (size_t)(r * 256 + wid * 64) * 16);
    }
    __syncthreads();
    bf16x8 af[4][2], bfv[4][2];
#pragma unroll
    for (int m = 0; m < 4; ++m)
#pragma unroll
      for (int kk = 0; kk < 2; ++kk)
        af[m][kk] = *(const bf16x8*)(AsB + (size_t)(wr * 64 + m * 16 + lcol) * 128
                                         + ((kk * 64 + lrow * 16) ^ sx));
#pragma unroll
    for (int n = 0; n < 4; ++n)
#pragma unroll
      for (int kk = 0; kk < 2; ++kk)
        bfv[n][kk] = *(const bf16x8*)(BsB + (size_t)(wc * 64 + n * 16 + lcol) * 128
                                          + ((kk * 64 + lrow * 16) ^ sx));
#pragma unroll
    for (int m = 0; m < 4; ++m)
#pragma unroll
      for (int n = 0; n < 4; ++n)
#pragma unroll
        for (int kk = 0; kk < 2; ++kk)
          acc[m][n] = __builtin_amdgcn_mfma_f32_16x16x32_bf16(af[m][kk], bfv[n][kk], acc[m][n], 0, 0, 0);
    __syncthreads();
  }

  if (seg == 2) {
#pragma unroll
    for (int m = 0; m < 4; ++m) {
#pragma unroll
      for (int n = 0; n < 4; ++n) {
        int col = col0 + wc * 64 + n * 16 + lcol;
        float bvv = bv[col];
        int row = row0 + wr * 64 + m * 16 + lrow * 4;
        u16x4 o;
#pragma unroll
        for (int j = 0; j < 4; ++j) o[j] = f2bf(acc[m][n][j] + bvv);
        *(u16x4*)(vtout + ((size_t)((row >> 11) * DIM + col)) * SLEN + (row & (SLEN - 1))) = o;
      }
    }
  } else {
    unsigned short* out = (seg == 0) ? qout : kout;
    const float* bias   = (seg == 0) ? bq : bk;
    const float  osc    = (seg == 0) ? qscale : 1.0f;
#pragma unroll
    for (int m = 0; m < 4; ++m) {
#pragma unroll
      for (int n = 0; n < 4; ++n) {
        int col = col0 + wc * 64 + n * 16 + lcol;
        float bvv = bias[col];
        int ip  = col >> 1;               // rotary pair index
        int odd = col & 1;
#pragma unroll
        for (int j = 0; j < 4; ++j) {
          int row = row0 + wr * 64 + m * 16 + lrow * 4 + j;
          int s   = row & (SLEN - 1);
          float v = acc[m][n][j] + bvv;
          float p = __shfl_xor(v, 1, 64);            // partner col (bias included)
          float c  = cosT[(size_t)s * (DIM / 2) + ip];
          float sn = sinT[(size_t)s * (DIM / 2) + ip];
          float o  = odd ? (v * c + p * sn) : (v * c - p * sn);
          out[(size_t)row * DIM + col] = f2bf(o * osc);
        }
      }
    }
  }
}

// ---------------- RoPE in-place (fallback path only) ----------------
__global__ __launch_bounds__(256) void rope_inplace(
    unsigned short* __restrict__ q,
    const float* __restrict__ cosT, const float* __restrict__ sinT, float scale) {
  int t   = blockIdx.x * 256 + threadIdx.x;
  int row = t >> 8;
  int e0  = (t & 255) * 8;
  int s   = row & (SLEN - 1);
  unsigned short* p = q + (size_t)row * DIM + e0;
  u16x8 v = *(u16x8*)p;
  f32x4 c  = *(const f32x4*)(cosT + (size_t)s * (DIM / 2) + (e0 >> 1));
  f32x4 sn = *(const f32x4*)(sinT + (size_t)s * (DIM / 2) + (e0 >> 1));
#pragma unroll
  for (int i = 0; i < 4; ++i) {
    float xe = bf2f(v[2 * i]), xo = bf2f(v[2 * i + 1]);
    float oe = (xe * c[i] - xo * sn[i]) * scale;
    float oo = (xo * c[i] + xe * sn[i]) * scale;
    v[2 * i] = f2bf(oe); v[2 * i + 1] = f2bf(oo);
  }
  *(u16x8*)p = v;
}

// ---------------- flash attention fwd (round-9 verbatim: 189.6 us measured) ----
__global__ __launch_bounds__(256) void attn_fwd(
    const unsigned short* __restrict__ Q,
    const unsigned short* __restrict__ Kg,
    const unsigned short* __restrict__ VtG,   // [(b*DIM + e)][SLEN]
    const float* __restrict__ mask,
    unsigned short* __restrict__ O)
{
  __shared__ __align__(16) unsigned short Ks[64][128];    // 16 KB
  __shared__ __align__(16) unsigned short Vts[128][64];   // 16 KB
  __shared__ __align__(16) unsigned short Ps[4][16][64];  // 8 KB per-wave P

  // T1 pane-grouping remap (bijective on 1024 = 8 XCDs x 128)
  int s0 = blockIdx.x + 32 * (blockIdx.y + 16 * blockIdx.z);
  int xc = s0 & 7, jj = s0 >> 3;
  int pane = xc * 4 + (jj >> 5);
  const int qt = jj & 31;
  const int h  = pane & 15, b = pane >> 4;

  const int tid = threadIdx.x, lane = tid & 63, wid = tid >> 6;
  const int lrow = lane >> 4, lcol = lane & 15;
  const int sx = (lcol & 7) << 4;            // read/store XOR (row = lcol everywhere)

  const unsigned short* Qb  = Q  + ((size_t)(b * SLEN + qt * 64)) * DIM + h * HDIM;
  const unsigned short* Kb  = Kg + (size_t)(b * SLEN) * DIM + h * HDIM;
  const unsigned short* Vtb = VtG + ((size_t)(b * DIM + h * HDIM)) * SLEN;
  const float* maskRow = mask + (size_t)(qt * 64 + wid * 16 + lcol) * SLEN;

  bf16x8 qf[4];
#pragma unroll
  for (int kk = 0; kk < 4; ++kk)
    qf[kk] = *(const bf16x8*)(Qb + (size_t)(wid * 16 + lcol) * DIM + kk * 32 + lrow * 8);

  float m_run = -1e30f, l_run = 0.f;   // per-lane, home q-row = lcol
  f32x4 acc_o[8] = {};

  char* KsB  = (char*)&Ks[0][0];
  char* VtsB = (char*)&Vts[0][0];
  char* PsB  = (char*)&Ps[0][0][0];

  for (int kt = 0; kt < SLEN / 64; ++kt) {
    __syncthreads();  // prior iteration's LDS reads done before overwrite
#pragma unroll
    for (int r = 0; r < 4; ++r) {
      int L = r * 256 + wid * 64 + lane;
      int krow = L >> 4, kc = (L & 15) ^ (krow & 7);
      gload16(Kb + (size_t)(kt * 64 + krow) * DIM + kc * 8,
              KsB + (size_t)(r * 256 + wid * 64) * 16);
    }
#pragma unroll
    for (int r = 0; r < 4; ++r) {
      int L = r * 256 + wid * 64 + lane;
      int d = L >> 3, vc = (L & 7) ^ (d & 7);
      gload16(Vtb + (size_t)d * SLEN + kt * 64 + vc * 8,
              VtsB + (size_t)(r * 256 + wid * 64) * 16);
    }
    __syncthreads();

    // S^T = K·Q^T: D[key][q], q = lcol, key = kn*16 + lrow*4 + r
    f32x4 sacc[4] = {};
#pragma unroll
    for (int kn = 0; kn < 4; ++kn)
#pragma unroll
      for (int kk = 0; kk < 4; ++kk) {
        bf16x8 kf = *(const bf16x8*)(KsB + (size_t)(kn * 16 + lcol) * 256
                                         + ((kk * 64 + lrow * 16) ^ sx));
        sacc[kn] = __builtin_amdgcn_mfma_f32_16x16x32_bf16(kf, qf[kk], sacc[kn], 0, 0, 0);
      }

    // mask add (vectorized f32x4 per kn)
    float sv[16];
#pragma unroll
    for (int kn = 0; kn < 4; ++kn) {
      f32x4 mv = *(const f32x4*)(maskRow + kt * 64 + kn * 16 + lrow * 4);
#pragma unroll
      for (int r = 0; r < 4; ++r) sv[kn * 4 + r] = sacc[kn][r] + mv[r];
    }

    // in-lane row max + 2 shfl (lanes lcol, lcol+16, lcol+32, lcol+48 share q-row)
    float pmax = sv[0];
#pragma unroll
    for (int i = 1; i < 16; ++i) pmax = fmaxf(pmax, sv[i]);
    pmax = fmaxf(pmax, __shfl_xor(pmax, 16, 64));
    pmax = fmaxf(pmax, __shfl_xor(pmax, 32, 64));

    // defer-max (T13): only rescale when some row's max grew past THR=8
    if (!__all(pmax - m_run <= 8.0f)) {
      float mnew = fmaxf(m_run, pmax);
      float alpha = __expf(m_run - mnew);
      m_run = mnew;
      l_run *= alpha;
      float ar[4];
#pragma unroll
      for (int r = 0; r < 4; ++r) ar[r] = __shfl(alpha, lrow * 4 + r, 64);
#pragma unroll
      for (int d = 0; d < 8; ++d) {
        f32x4 t = acc_o[d];
#pragma unroll
        for (int r = 0; r < 4; ++r) t[r] *= ar[r];
        acc_o[d] = t;
      }
    }

    // exp + row sum (in-lane + 2 shfl)
    float pv[16];
    float rsum = 0.f;
#pragma unroll
    for (int i = 0; i < 16; ++i) { float pe = __expf(sv[i] - m_run); pv[i] = pe; rsum += pe; }
    rsum += __shfl_xor(rsum, 16, 64);
    rsum += __shfl_xor(rsum, 32, 64);
    l_run += rsum;

    // P store: row = q = lcol, k = kn*16 + lrow*4 + r, swizzled by sx
#pragma unroll
    for (int kn = 0; kn < 4; ++kn)
#pragma unroll
      for (int r = 0; r < 4; ++r)
        *(unsigned short*)(PsB + wid * 2048 + lcol * 128
                           + ((kn * 32 + (lrow * 4 + r) * 2) ^ sx)) = f2bf(pv[kn * 4 + r]);
    // no barrier: Ps[wid] written+read by the same wave

    // PV: A = P (16x64), B = V^T rows (d)
    bf16x8 pf[2];
#pragma unroll
    for (int ks = 0; ks < 2; ++ks)
      pf[ks] = *(const bf16x8*)(PsB + wid * 2048 + lcol * 128
                                + ((ks * 64 + lrow * 16) ^ sx));
#pragma unroll
    for (int d = 0; d < 8; ++d)
#pragma unroll
      for (int ks = 0; ks < 2; ++ks) {
        bf16x8 vf = *(const bf16x8*)(VtsB + (size_t)(d * 16 + lcol) * 128
                                          + ((ks * 64 + lrow * 16) ^ sx));
        acc_o[d] = __builtin_amdgcn_mfma_f32_16x16x32_bf16(pf[ks], vf, acc_o[d], 0, 0, 0);
      }
  }

  // epilogue: O[q][d], q = wid*16 + lrow*4 + r, d = d*16 + lcol; l via shfl from home lanes
  float linv[4];
#pragma unroll
  for (int r = 0; r < 4; ++r) linv[r] = 1.0f / __shfl(l_run, lrow * 4 + r, 64);
  int orow0 = b * SLEN + qt * 64 + wid * 16 + lrow * 4;
#pragma unroll
  for (int d = 0; d < 8; ++d)
#pragma unroll
    for (int r = 0; r < 4; ++r) {
      float o = acc_o[d][r] * linv[r];
      O[(size_t)(orow0 + r) * DIM + h * HDIM + d * 16 + lcol] = f2bf(o);
    }
}

// ---------------- launch ----------------
extern "C" void kernel_launch(void* const* d_in, const int* in_sizes, int n_in,
                              void* d_out, int out_size, void* d_ws, size_t ws_size,
                              hipStream_t stream) {
  const float* x    = (const float*)d_in[0];
  const float* cosT = (const float*)d_in[1];
  const float* sinT = (const float*)d_in[2];
  const float* mask = (const float*)d_in[3];
  const float* Wq   = (const float*)d_in[4];
  const float* bq   = (const float*)d_in[5];
  const float* Wk   = (const float*)d_in[6];
  const float* bk   = (const float*)d_in[7];
  const float* Wv   = (const float*)d_in[8];
  const float* bv   = (const float*)d_in[9];
  const float* Wo   = (const float*)d_in[10];
  const float* bo   = (const float*)d_in[11];

  const size_t MB = 1u << 20;
  if (ws_size < 72 * MB) return;

  char* ws = (char*)d_ws;
  unsigned short* xb = (unsigned short*)(ws);            // 16 MB (reused as Ob after attn)
  unsigned short* qb = (unsigned short*)(ws + 16 * MB);  // 16 MB
  unsigned short* kb = (unsigned short*)(ws + 32 * MB);  // 16 MB
  unsigned short* Vt = (unsigned short*)(ws + 48 * MB);  // 16 MB (V pre-transposed per head)
  unsigned short* Ob = xb;

  const float scale = 0.08838834764831845f;  // 1/sqrt(128)

  if (ws_size >= 88 * MB) {
    // fused path: one conversion dispatch (x + Wq + Wk + Wv), fused QKV+RoPE GEMM
    unsigned short* Wb3 = (unsigned short*)(ws + 64 * MB);   // 24 MB
    conv4_f32_bf16<<<20480, 256, 0, stream>>>(x, Wq, Wk, Wv, xb, Wb3);
    gemm_qkv<<<dim3(MROWS / 128, 48), 256, 0, stream>>>(xb, Wb3, bq, bk, bv,
                                                        cosT, sinT, scale, qb, kb, Vt);
    attn_fwd<<<dim3(SLEN / 64, NHEAD, BATCH), 256, 0, stream>>>(qb, kb, Vt, mask, Ob);
    conv_f32_bf16<<<4096, 256, 0, stream>>>(Wo, Wb3, (DIM * DIM) / 4);
    gemm_bt<0><<<dim3(MROWS / 128, DIM / 128), 256, 0, stream>>>(Ob, Wb3, bo, d_out, MROWS, DIM, DIM);
  } else {
    // fallback (72 MB): unfused sequence
    unsigned short* Wb = (unsigned short*)(ws + 64 * MB);
    dim3 gGemm(MROWS / 128, DIM / 128);
    conv_f32_bf16<<<8192, 256, 0, stream>>>(x, xb, (MROWS * DIM) / 4);
    conv_f32_bf16<<<4096, 256, 0, stream>>>(Wq, Wb, (DIM * DIM) / 4);
    gemm_bt<1><<<gGemm, 256, 0, stream>>>(xb, Wb, bq, qb, MROWS, DIM, DIM);
    conv_f32_bf16<<<4096, 256, 0, stream>>>(Wk, Wb, (DIM * DIM) / 4);
    gemm_bt<1><<<gGemm, 256, 0, stream>>>(xb, Wb, bk, kb, MROWS, DIM, DIM);
    conv_f32_bf16<<<4096, 256, 0, stream>>>(Wv, Wb, (DIM * DIM) / 4);
    gemm_bt<2><<<gGemm, 256, 0, stream>>>(xb, Wb, bv, Vt, MROWS, DIM, DIM);
    rope_inplace<<<4096, 256, 0, stream>>>(qb, cosT, sinT, scale);
    rope_inplace<<<4096, 256, 0, stream>>>(kb, cosT, sinT, 1.0f);
    attn_fwd<<<dim3(SLEN / 64, NHEAD, BATCH), 256, 0, stream>>>(qb, kb, Vt, mask, Ob);
    conv_f32_bf16<<<4096, 256, 0, stream>>>(Wo, Wb, (DIM * DIM) / 4);
    gemm_bt<0><<<gGemm, 256, 0, stream>>>(Ob, Wb, bo, d_out, MROWS, DIM, DIM);
  }
}

// Round 13
// 365.164 us; speedup vs baseline: 1.1656x; 1.0445x over previous
//
#include <hip/hip_runtime.h>

#define DIM   2048
#define SLEN  2048
#define BATCH 2
#define NHEAD 16
#define HDIM  128
#define MROWS (BATCH*SLEN)   // 4096

typedef __attribute__((ext_vector_type(8))) __bf16 bf16x8;
typedef __attribute__((ext_vector_type(4))) float  f32x4;
typedef __attribute__((ext_vector_type(8))) unsigned short u16x8;
typedef __attribute__((ext_vector_type(4))) unsigned short u16x4;

__device__ __forceinline__ unsigned short f2bf(float f) {
  union { float f; unsigned u; } v; v.f = f;
  unsigned r = v.u + 0x7FFFu + ((v.u >> 16) & 1u);   // RTNE
  return (unsigned short)(r >> 16);
}
__device__ __forceinline__ float bf2f(unsigned short h) {
  union { unsigned u; float f; } v; v.u = ((unsigned)h) << 16;
  return v.f;
}
__device__ __forceinline__ void gload16(const void* g, void* l) {
  __builtin_amdgcn_global_load_lds(
      (const __attribute__((address_space(1))) void*)g,
      (__attribute__((address_space(3))) void*)l, 16, 0, 0);
}

// ---------------- fp32 -> bf16 convert (vectorized) ----------------
__global__ __launch_bounds__(256) void conv_f32_bf16(
    const float* __restrict__ in, unsigned short* __restrict__ out, int n4) {
  int t = blockIdx.x * 256 + threadIdx.x;
  if (t >= n4) return;
  f32x4 v = *(const f32x4*)(in + (size_t)t * 4);
  u16x4 o;
  o[0] = f2bf(v[0]); o[1] = f2bf(v[1]); o[2] = f2bf(v[2]); o[3] = f2bf(v[3]);
  *(u16x4*)(out + (size_t)t * 4) = o;
}

// ---------------- fused conversion: x + Wq + Wk + Wv (+ optional Wo) in ONE dispatch ----
// grid = 8192 (x) + 4*4096 (weights) = 24576 blocks when Wo slot available.
__global__ __launch_bounds__(256) void conv5_f32_bf16(
    const float* __restrict__ x,
    const float* __restrict__ Wq, const float* __restrict__ Wk, const float* __restrict__ Wv,
    const float* __restrict__ Wo,
    unsigned short* __restrict__ xb, unsigned short* __restrict__ Wb3,
    unsigned short* __restrict__ Wob) {
  int blk = blockIdx.x;
  const float* src; unsigned short* dst; int idx;
  if (blk < 8192)       { src = x;  dst = xb;                            idx = blk; }
  else if (blk < 12288) { src = Wq; dst = Wb3;                           idx = blk - 8192; }
  else if (blk < 16384) { src = Wk; dst = Wb3 + (size_t)DIM * DIM;       idx = blk - 12288; }
  else if (blk < 20480) { src = Wv; dst = Wb3 + (size_t)2 * DIM * DIM;   idx = blk - 16384; }
  else                  { src = Wo; dst = Wob;                           idx = blk - 20480; }
  int t = idx * 256 + threadIdx.x;
  f32x4 v = *(const f32x4*)(src + (size_t)t * 4);
  u16x4 o;
  o[0] = f2bf(v[0]); o[1] = f2bf(v[1]); o[2] = f2bf(v[2]); o[3] = f2bf(v[3]);
  *(u16x4*)(dst + (size_t)t * 4) = o;
}

// ---------------- bf16 GEMM (BK=64, swizzled staging): C = A * Bw^T + bias ----------------
// OUT_MODE: 0 = f32 row-major, 1 = bf16 row-major, 2 = bf16 transposed-per-batch
template<int OUT_MODE>
__global__ __launch_bounds__(256) void gemm_bt(
    const unsigned short* __restrict__ A,
    const unsigned short* __restrict__ Bw,
    const float* __restrict__ bias,
    void* __restrict__ Cout, int M, int N, int K)
{
  __shared__ __align__(16) unsigned short As[128][64];   // 16 KB
  __shared__ __align__(16) unsigned short Bs[128][64];   // 16 KB
  const int tid  = threadIdx.x;
  const int lane = tid & 63;
  const int wid  = tid >> 6;
  const int wr   = wid >> 1, wc = wid & 1;
  const int lrow = lane >> 4, lcol = lane & 15;
  const int sx   = (lcol & 7) << 4;

  const int gx = gridDim.x;
  int bid = blockIdx.y * gx + blockIdx.x;
  int nwg = gx * gridDim.y;
  int swz = (bid & 7) * (nwg >> 3) + (bid >> 3);     // T1 (nwg%8==0)
  const int row0 = (swz % gx) * 128, col0 = (swz / gx) * 128;

  f32x4 acc[4][4] = {};

  const unsigned short* Ablk = A  + (size_t)row0 * K;
  const unsigned short* Bblk = Bw + (size_t)col0 * K;
  char* AsB = (char*)&As[0][0];
  char* BsB = (char*)&Bs[0][0];

  for (int k0 = 0; k0 < K; k0 += 64) {
#pragma unroll
    for (int r = 0; r < 4; ++r) {
      int L = r * 256 + wid * 64 + lane;               // chunk id; row=L>>3, c=L&7
      int row = L >> 3, cs = (L & 7) ^ (row & 7);
      gload16(Ablk + (size_t)row * K + k0 + cs * 8, AsB + (size_t)(r * 256 + wid * 64) * 16);
      gload16(Bblk + (size_t)row * K + k0 + cs * 8, BsB + (size_t)(r * 256 + wid * 64) * 16);
    }
    __syncthreads();
    bf16x8 af[4][2], bfv[4][2];
#pragma unroll
    for (int m = 0; m < 4; ++m)
#pragma unroll
      for (int kk = 0; kk < 2; ++kk)
        af[m][kk] = *(const bf16x8*)(AsB + (size_t)(wr * 64 + m * 16 + lcol) * 128
                                         + ((kk * 64 + lrow * 16) ^ sx));
#pragma unroll
    for (int n = 0; n < 4; ++n)
#pragma unroll
      for (int kk = 0; kk < 2; ++kk)
        bfv[n][kk] = *(const bf16x8*)(BsB + (size_t)(wc * 64 + n * 16 + lcol) * 128
                                          + ((kk * 64 + lrow * 16) ^ sx));
#pragma unroll
    for (int m = 0; m < 4; ++m)
#pragma unroll
      for (int n = 0; n < 4; ++n)
#pragma unroll
        for (int kk = 0; kk < 2; ++kk)
          acc[m][n] = __builtin_amdgcn_mfma_f32_16x16x32_bf16(af[m][kk], bfv[n][kk], acc[m][n], 0, 0, 0);
    __syncthreads();
  }

#pragma unroll
  for (int m = 0; m < 4; ++m) {
#pragma unroll
    for (int n = 0; n < 4; ++n) {
      int col = col0 + wc * 64 + n * 16 + lcol;
      float bv = bias[col];
      if (OUT_MODE == 2) {
        int row = row0 + wr * 64 + m * 16 + lrow * 4;
        u16x4 o;
#pragma unroll
        for (int j = 0; j < 4; ++j) o[j] = f2bf(acc[m][n][j] + bv);
        *(u16x4*)((unsigned short*)Cout +
                  ((size_t)((row >> 11) * DIM + col)) * SLEN + (row & (SLEN - 1))) = o;
      } else {
#pragma unroll
        for (int j = 0; j < 4; ++j) {
          int row = row0 + wr * 64 + m * 16 + lrow * 4 + j;
          float val = acc[m][n][j] + bv;
          if (OUT_MODE == 1) ((unsigned short*)Cout)[(size_t)row * N + col] = f2bf(val);
          else               ((float*)Cout)[(size_t)row * N + col] = val;
        }
      }
    }
  }
}

// ---------------- fused QKV GEMM + RoPE epilogue (BK=64, swizzled staging) ----------------
__global__ __launch_bounds__(256) void gemm_qkv(
    const unsigned short* __restrict__ A,
    const unsigned short* __restrict__ Bw3,   // [3*DIM][DIM] bf16
    const float* __restrict__ bq, const float* __restrict__ bk, const float* __restrict__ bv,
    const float* __restrict__ cosT, const float* __restrict__ sinT, float qscale,
    unsigned short* __restrict__ qout,
    unsigned short* __restrict__ kout,
    unsigned short* __restrict__ vtout)
{
  __shared__ __align__(16) unsigned short As[128][64];
  __shared__ __align__(16) unsigned short Bs[128][64];
  const int tid  = threadIdx.x;
  const int lane = tid & 63;
  const int wid  = tid >> 6;
  const int wr   = wid >> 1, wc = wid & 1;
  const int lrow = lane >> 4, lcol = lane & 15;
  const int sx   = (lcol & 7) << 4;

  int bid = blockIdx.y * 32 + blockIdx.x;            // grid (32,48), nwg=1536
  int swz = (bid & 7) * 192 + (bid >> 3);            // T1 bijective
  const int row0 = (swz & 31) * 128;
  const int by   = swz >> 5;
  const int seg  = by >> 4;             // 0=q, 1=k, 2=v
  const int col0 = (by & 15) * 128;     // column within segment

  f32x4 acc[4][4] = {};

  const unsigned short* Ablk = A   + (size_t)row0 * DIM;
  const unsigned short* Bblk = Bw3 + (size_t)by * 128 * DIM;
  char* AsB = (char*)&As[0][0];
  char* BsB = (char*)&Bs[0][0];

  for (int k0 = 0; k0 < DIM; k0 += 64) {
#pragma unroll
    for (int r = 0; r < 4; ++r) {
      int L = r * 256 + wid * 64 + lane;
      int row = L >> 3, cs = (L & 7) ^ (row & 7);
      gload16(Ablk + (size_t)row * DIM + k0 + cs * 8, AsB + (size_t)(r * 256 + wid * 64) * 16);
      gload16(Bblk + (size_t)row * DIM + k0 + cs * 8, BsB + (size_t)(r * 256 + wid * 64) * 16);
    }
    __syncthreads();
    bf16x8 af[4][2], bfv[4][2];
#pragma unroll
    for (int m = 0; m < 4; ++m)
#pragma unroll
      for (int kk = 0; kk < 2; ++kk)
        af[m][kk] = *(const bf16x8*)(AsB + (size_t)(wr * 64 + m * 16 + lcol) * 128
                                         + ((kk * 64 + lrow * 16) ^ sx));
#pragma unroll
    for (int n = 0; n < 4; ++n)
#pragma unroll
      for (int kk = 0; kk < 2; ++kk)
        bfv[n][kk] = *(const bf16x8*)(BsB + (size_t)(wc * 64 + n * 16 + lcol) * 128
                                          + ((kk * 64 + lrow * 16) ^ sx));
#pragma unroll
    for (int m = 0; m < 4; ++m)
#pragma unroll
      for (int n = 0; n < 4; ++n)
#pragma unroll
        for (int kk = 0; kk < 2; ++kk)
          acc[m][n] = __builtin_amdgcn_mfma_f32_16x16x32_bf16(af[m][kk], bfv[n][kk], acc[m][n], 0, 0, 0);
    __syncthreads();
  }

  if (seg == 2) {
#pragma unroll
    for (int m = 0; m < 4; ++m) {
#pragma unroll
      for (int n = 0; n < 4; ++n) {
        int col = col0 + wc * 64 + n * 16 + lcol;
        float bvv = bv[col];
        int row = row0 + wr * 64 + m * 16 + lrow * 4;
        u16x4 o;
#pragma unroll
        for (int j = 0; j < 4; ++j) o[j] = f2bf(acc[m][n][j] + bvv);
        *(u16x4*)(vtout + ((size_t)((row >> 11) * DIM + col)) * SLEN + (row & (SLEN - 1))) = o;
      }
    }
  } else {
    unsigned short* out = (seg == 0) ? qout : kout;
    const float* bias   = (seg == 0) ? bq : bk;
    const float  osc    = (seg == 0) ? qscale : 1.0f;
#pragma unroll
    for (int m = 0; m < 4; ++m) {
#pragma unroll
      for (int n = 0; n < 4; ++n) {
        int col = col0 + wc * 64 + n * 16 + lcol;
        float bvv = bias[col];
        int ip  = col >> 1;               // rotary pair index
        int odd = col & 1;
#pragma unroll
        for (int j = 0; j < 4; ++j) {
          int row = row0 + wr * 64 + m * 16 + lrow * 4 + j;
          int s   = row & (SLEN - 1);
          float v = acc[m][n][j] + bvv;
          float p = __shfl_xor(v, 1, 64);            // partner col (bias included)
          float c  = cosT[(size_t)s * (DIM / 2) + ip];
          float sn = sinT[(size_t)s * (DIM / 2) + ip];
          float o  = odd ? (v * c + p * sn) : (v * c - p * sn);
          out[(size_t)row * DIM + col] = f2bf(o * osc);
        }
      }
    }
  }
}

// ---------------- RoPE in-place (fallback path only) ----------------
__global__ __launch_bounds__(256) void rope_inplace(
    unsigned short* __restrict__ q,
    const float* __restrict__ cosT, const float* __restrict__ sinT, float scale) {
  int t   = blockIdx.x * 256 + threadIdx.x;
  int row = t >> 8;
  int e0  = (t & 255) * 8;
  int s   = row & (SLEN - 1);
  unsigned short* p = q + (size_t)row * DIM + e0;
  u16x8 v = *(u16x8*)p;
  f32x4 c  = *(const f32x4*)(cosT + (size_t)s * (DIM / 2) + (e0 >> 1));
  f32x4 sn = *(const f32x4*)(sinT + (size_t)s * (DIM / 2) + (e0 >> 1));
#pragma unroll
  for (int i = 0; i < 4; ++i) {
    float xe = bf2f(v[2 * i]), xo = bf2f(v[2 * i + 1]);
    float oe = (xe * c[i] - xo * sn[i]) * scale;
    float oo = (xo * c[i] + xe * sn[i]) * scale;
    v[2 * i] = f2bf(oe); v[2 * i + 1] = f2bf(oo);
  }
  *(u16x8*)p = v;
}

// ---------------- flash attention fwd (round-9 verbatim: 189.6 us measured) ----
__global__ __launch_bounds__(256) void attn_fwd(
    const unsigned short* __restrict__ Q,
    const unsigned short* __restrict__ Kg,
    const unsigned short* __restrict__ VtG,   // [(b*DIM + e)][SLEN]
    const float* __restrict__ mask,
    unsigned short* __restrict__ O)
{
  __shared__ __align__(16) unsigned short Ks[64][128];    // 16 KB
  __shared__ __align__(16) unsigned short Vts[128][64];   // 16 KB
  __shared__ __align__(16) unsigned short Ps[4][16][64];  // 8 KB per-wave P

  // T1 pane-grouping remap (bijective on 1024 = 8 XCDs x 128)
  int s0 = blockIdx.x + 32 * (blockIdx.y + 16 * blockIdx.z);
  int xc = s0 & 7, jj = s0 >> 3;
  int pane = xc * 4 + (jj >> 5);
  const int qt = jj & 31;
  const int h  = pane & 15, b = pane >> 4;

  const int tid = threadIdx.x, lane = tid & 63, wid = tid >> 6;
  const int lrow = lane >> 4, lcol = lane & 15;
  const int sx = (lcol & 7) << 4;            // read/store XOR (row = lcol everywhere)

  const unsigned short* Qb  = Q  + ((size_t)(b * SLEN + qt * 64)) * DIM + h * HDIM;
  const unsigned short* Kb  = Kg + (size_t)(b * SLEN) * DIM + h * HDIM;
  const unsigned short* Vtb = VtG + ((size_t)(b * DIM + h * HDIM)) * SLEN;
  const float* maskRow = mask + (size_t)(qt * 64 + wid * 16 + lcol) * SLEN;

  bf16x8 qf[4];
#pragma unroll
  for (int kk = 0; kk < 4; ++kk)
    qf[kk] = *(const bf16x8*)(Qb + (size_t)(wid * 16 + lcol) * DIM + kk * 32 + lrow * 8);

  float m_run = -1e30f, l_run = 0.f;   // per-lane, home q-row = lcol
  f32x4 acc_o[8] = {};

  char* KsB  = (char*)&Ks[0][0];
  char* VtsB = (char*)&Vts[0][0];
  char* PsB  = (char*)&Ps[0][0][0];

  for (int kt = 0; kt < SLEN / 64; ++kt) {
    __syncthreads();  // prior iteration's LDS reads done before overwrite
#pragma unroll
    for (int r = 0; r < 4; ++r) {
      int L = r * 256 + wid * 64 + lane;
      int krow = L >> 4, kc = (L & 15) ^ (krow & 7);
      gload16(Kb + (size_t)(kt * 64 + krow) * DIM + kc * 8,
              KsB + (size_t)(r * 256 + wid * 64) * 16);
    }
#pragma unroll
    for (int r = 0; r < 4; ++r) {
      int L = r * 256 + wid * 64 + lane;
      int d = L >> 3, vc = (L & 7) ^ (d & 7);
      gload16(Vtb + (size_t)d * SLEN + kt * 64 + vc * 8,
              VtsB + (size_t)(r * 256 + wid * 64) * 16);
    }
    __syncthreads();

    // S^T = K·Q^T: D[key][q], q = lcol, key = kn*16 + lrow*4 + r
    f32x4 sacc[4] = {};
#pragma unroll
    for (int kn = 0; kn < 4; ++kn)
#pragma unroll
      for (int kk = 0; kk < 4; ++kk) {
        bf16x8 kf = *(const bf16x8*)(KsB + (size_t)(kn * 16 + lcol) * 256
                                         + ((kk * 64 + lrow * 16) ^ sx));
        sacc[kn] = __builtin_amdgcn_mfma_f32_16x16x32_bf16(kf, qf[kk], sacc[kn], 0, 0, 0);
      }

    // mask add (vectorized f32x4 per kn)
    float sv[16];
#pragma unroll
    for (int kn = 0; kn < 4; ++kn) {
      f32x4 mv = *(const f32x4*)(maskRow + kt * 64 + kn * 16 + lrow * 4);
#pragma unroll
      for (int r = 0; r < 4; ++r) sv[kn * 4 + r] = sacc[kn][r] + mv[r];
    }

    // in-lane row max + 2 shfl (lanes lcol, lcol+16, lcol+32, lcol+48 share q-row)
    float pmax = sv[0];
#pragma unroll
    for (int i = 1; i < 16; ++i) pmax = fmaxf(pmax, sv[i]);
    pmax = fmaxf(pmax, __shfl_xor(pmax, 16, 64));
    pmax = fmaxf(pmax, __shfl_xor(pmax, 32, 64));

    // defer-max (T13): only rescale when some row's max grew past THR=8
    if (!__all(pmax - m_run <= 8.0f)) {
      float mnew = fmaxf(m_run, pmax);
      float alpha = __expf(m_run - mnew);
      m_run = mnew;
      l_run *= alpha;
      float ar[4];
#pragma unroll
      for (int r = 0; r < 4; ++r) ar[r] = __shfl(alpha, lrow * 4 + r, 64);
#pragma unroll
      for (int d = 0; d < 8; ++d) {
        f32x4 t = acc_o[d];
#pragma unroll
        for (int r = 0; r < 4; ++r) t[r] *= ar[r];
        acc_o[d] = t;
      }
    }

    // exp + row sum (in-lane + 2 shfl)
    float pv[16];
    float rsum = 0.f;
#pragma unroll
    for (int i = 0; i < 16; ++i) { float pe = __expf(sv[i] - m_run); pv[i] = pe; rsum += pe; }
    rsum += __shfl_xor(rsum, 16, 64);
    rsum += __shfl_xor(rsum, 32, 64);
    l_run += rsum;

    // P store: row = q = lcol, k = kn*16 + lrow*4 + r, swizzled by sx
#pragma unroll
    for (int kn = 0; kn < 4; ++kn)
#pragma unroll
      for (int r = 0; r < 4; ++r)
        *(unsigned short*)(PsB + wid * 2048 + lcol * 128
                           + ((kn * 32 + (lrow * 4 + r) * 2) ^ sx)) = f2bf(pv[kn * 4 + r]);
    // no barrier: Ps[wid] written+read by the same wave

    // PV: A = P (16x64), B = V^T rows (d)
    bf16x8 pf[2];
#pragma unroll
    for (int ks = 0; ks < 2; ++ks)
      pf[ks] = *(const bf16x8*)(PsB + wid * 2048 + lcol * 128
                                + ((ks * 64 + lrow * 16) ^ sx));
#pragma unroll
    for (int d = 0; d < 8; ++d)
#pragma unroll
      for (int ks = 0; ks < 2; ++ks) {
        bf16x8 vf = *(const bf16x8*)(VtsB + (size_t)(d * 16 + lcol) * 128
                                          + ((ks * 64 + lrow * 16) ^ sx));
        acc_o[d] = __builtin_amdgcn_mfma_f32_16x16x32_bf16(pf[ks], vf, acc_o[d], 0, 0, 0);
      }
  }

  // epilogue: O[q][d], q = wid*16 + lrow*4 + r, d = d*16 + lcol; l via shfl from home lanes
  float linv[4];
#pragma unroll
  for (int r = 0; r < 4; ++r) linv[r] = 1.0f / __shfl(l_run, lrow * 4 + r, 64);
  int orow0 = b * SLEN + qt * 64 + wid * 16 + lrow * 4;
#pragma unroll
  for (int d = 0; d < 8; ++d)
#pragma unroll
    for (int r = 0; r < 4; ++r) {
      float o = acc_o[d][r] * linv[r];
      O[(size_t)(orow0 + r) * DIM + h * HDIM + d * 16 + lcol] = f2bf(o);
    }
}

// ---------------- launch ----------------
extern "C" void kernel_launch(void* const* d_in, const int* in_sizes, int n_in,
                              void* d_out, int out_size, void* d_ws, size_t ws_size,
                              hipStream_t stream) {
  const float* x    = (const float*)d_in[0];
  const float* cosT = (const float*)d_in[1];
  const float* sinT = (const float*)d_in[2];
  const float* mask = (const float*)d_in[3];
  const float* Wq   = (const float*)d_in[4];
  const float* bq   = (const float*)d_in[5];
  const float* Wk   = (const float*)d_in[6];
  const float* bk   = (const float*)d_in[7];
  const float* Wv   = (const float*)d_in[8];
  const float* bv   = (const float*)d_in[9];
  const float* Wo   = (const float*)d_in[10];
  const float* bo   = (const float*)d_in[11];

  const size_t MB = 1u << 20;
  if (ws_size < 72 * MB) return;

  char* ws = (char*)d_ws;
  unsigned short* xb = (unsigned short*)(ws);            // 16 MB (reused as Ob after attn)
  unsigned short* qb = (unsigned short*)(ws + 16 * MB);  // 16 MB
  unsigned short* kb = (unsigned short*)(ws + 32 * MB);  // 16 MB
  unsigned short* Vt = (unsigned short*)(ws + 48 * MB);  // 16 MB (V pre-transposed per head)
  unsigned short* Ob = xb;

  const float scale = 0.08838834764831845f;  // 1/sqrt(128)

  if (ws_size >= 96 * MB) {
    // fully fused path: one conversion dispatch (x + Wq/Wk/Wv + Wo), QKV+RoPE GEMM
    unsigned short* Wb3 = (unsigned short*)(ws + 64 * MB);   // 24 MB
    unsigned short* Wob = (unsigned short*)(ws + 88 * MB);   // 8 MB
    conv5_f32_bf16<<<24576, 256, 0, stream>>>(x, Wq, Wk, Wv, Wo, xb, Wb3, Wob);
    gemm_qkv<<<dim3(MROWS / 128, 48), 256, 0, stream>>>(xb, Wb3, bq, bk, bv,
                                                        cosT, sinT, scale, qb, kb, Vt);
    attn_fwd<<<dim3(SLEN / 64, NHEAD, BATCH), 256, 0, stream>>>(qb, kb, Vt, mask, Ob);
    gemm_bt<0><<<dim3(MROWS / 128, DIM / 128), 256, 0, stream>>>(Ob, Wob, bo, d_out, MROWS, DIM, DIM);
  } else if (ws_size >= 88 * MB) {
    // fused path without Wo slot (round-12 behavior)
    unsigned short* Wb3 = (unsigned short*)(ws + 64 * MB);   // 24 MB
    conv5_f32_bf16<<<20480, 256, 0, stream>>>(x, Wq, Wk, Wv, Wo, xb, Wb3, Wb3); // Wo part not launched (grid<20481)
    gemm_qkv<<<dim3(MROWS / 128, 48), 256, 0, stream>>>(xb, Wb3, bq, bk, bv,
                                                        cosT, sinT, scale, qb, kb, Vt);
    attn_fwd<<<dim3(SLEN / 64, NHEAD, BATCH), 256, 0, stream>>>(qb, kb, Vt, mask, Ob);
    conv_f32_bf16<<<4096, 256, 0, stream>>>(Wo, Wb3, (DIM * DIM) / 4);
    gemm_bt<0><<<dim3(MROWS / 128, DIM / 128), 256, 0, stream>>>(Ob, Wb3, bo, d_out, MROWS, DIM, DIM);
  } else {
    // fallback (72 MB): unfused sequence
    unsigned short* Wb = (unsigned short*)(ws + 64 * MB);
    dim3 gGemm(MROWS / 128, DIM / 128);
    conv_f32_bf16<<<8192, 256, 0, stream>>>(x, xb, (MROWS * DIM) / 4);
    conv_f32_bf16<<<4096, 256, 0, stream>>>(Wq, Wb, (DIM * DIM) / 4);
    gemm_bt<1><<<gGemm, 256, 0, stream>>>(xb, Wb, bq, qb, MROWS, DIM, DIM);
    conv_f32_bf16<<<4096, 256, 0, stream>>>(Wk, Wb, (DIM * DIM) / 4);
    gemm_bt<1><<<gGemm, 256, 0, stream>>>(xb, Wb, bk, kb, MROWS, DIM, DIM);
    conv_f32_bf16<<<4096, 256, 0, stream>>>(Wv, Wb, (DIM * DIM) / 4);
    gemm_bt<2><<<gGemm, 256, 0, stream>>>(xb, Wb, bv, Vt, MROWS, DIM, DIM);
    rope_inplace<<<4096, 256, 0, stream>>>(qb, cosT, sinT, scale);
    rope_inplace<<<4096, 256, 0, stream>>>(kb, cosT, sinT, 1.0f);
    attn_fwd<<<dim3(SLEN / 64, NHEAD, BATCH), 256, 0, stream>>>(qb, kb, Vt, mask, Ob);
    conv_f32_bf16<<<4096, 256, 0, stream>>>(Wo, Wb, (DIM * DIM) / 4);
    gemm_bt<0><<<gGemm, 256, 0, stream>>>(Ob, Wb, bo, d_out, MROWS, DIM, DIM);
  }
}